// Round 2
// baseline (59522.205 us; speedup 1.0000x reference)
//
#include <hip/hip_runtime.h>

typedef unsigned int   u32;
typedef unsigned short u16;
typedef float  f32x4  __attribute__((ext_vector_type(4)));
typedef __bf16 bf16x8 __attribute__((ext_vector_type(8)));
static_assert(sizeof(bf16x8) == 16, "bf16x8 must be 16B");

#define DEV static __device__ __forceinline__

constexpr int BN = 64;     // batch
constexpr int TN = 128;    // time steps
constexpr int DN = 256;    // input/latent dim
constexpr int HN = 1024;   // hidden
constexpr size_t BTD = (size_t)BN * TN * DN;   // 2097152

// ---------- bf16 helpers (RNE) ----------
DEV u16 f2b(float f) {
    u32 u = __builtin_bit_cast(u32, f);
    u += 0x7fffu + ((u >> 16) & 1u);
    return (u16)(u >> 16);
}
DEV float b2f(u16 h) { u32 u = ((u32)h) << 16; return __builtin_bit_cast(float, u); }
DEV void split2(float v, u16 &hi, u16 &lo) { u16 h = f2b(v); hi = h; lo = f2b(v - b2f(h)); }
DEV bf16x8 ldfrag(const u16 *p) { return __builtin_bit_cast(bf16x8, *reinterpret_cast<const uint4 *>(p)); }
DEV float sigm(float x) { return 1.0f / (1.0f + __expf(-x)); }
#define MFMA16(a, b, c) __builtin_amdgcn_mfma_f32_16x16x32_bf16((a), (b), (c), 0, 0, 0)

// ---------- zero scratch ----------
__global__ void zero_ws(uint4 *p, size_t n16) {
    size_t i = (size_t)blockIdx.x * blockDim.x + threadIdx.x;
    size_t st = (size_t)gridDim.x * blockDim.x;
    uint4 z; z.x = z.y = z.z = z.w = 0u;
    for (; i < n16; i += st) p[i] = z;
}

// ---------- prep t=0 encoder input (x_0 and x_hat_0 = x_0 - 0.5) ----------
__global__ void prep_x0(const float *__restrict__ x, u16 *__restrict__ ahi, u16 *__restrict__ alo) {
    int idx = blockIdx.x * 256 + threadIdx.x;          // 64*256 = 16384
    int row = idx >> 8, col = idx & 255;
    float xv = x[((size_t)row * TN) * DN + col];       // x[row][0][col]
    float xh = xv - 0.5f;                              // x0 - sigmoid(0)
    u16 h, l;
    split2(xv, h, l); ahi[row * 1536 + col] = h;        alo[row * 1536 + col] = l;
    split2(xh, h, l); ahi[row * 1536 + 256 + col] = h;  alo[row * 1536 + 256 + col] = l;
}

// ---------- pack fp32 weights -> bf16 hi/lo in MFMA fragment order ----------
// packed elem (n',k): nt=n'>>4, nl=n'&15, kt=k>>5, ko=k&31 ; lane=nl+16*(ko>>3)
// idx = ((nt*KTILES + kt)*64 + lane)*8 + (ko&7)
// mode 0: n'=n ; mode 1 (LSTM gate perm, n=g*1024+j): n'=(j>>4)*64+g*16+(j&15)
// mode 2 (W_mu):  n'=(n>>5)*64+(n&31) ; mode 3 (W_logvar): n'=(n>>5)*64+32+(n&31)
__global__ void pack_w(const float *__restrict__ src, u16 *__restrict__ dhi, u16 *__restrict__ dlo,
                       int Nsrc, int Ksrc, int koff, int ktiles, int mode) {
    int idx = blockIdx.x * 256 + threadIdx.x;
    if (idx >= Nsrc * Ksrc) return;
    int n = idx / Ksrc, k = idx - n * Ksrc;
    float v = src[idx];
    int np;
    if (mode == 1)      { int g = n >> 10, j = n & 1023; np = ((j >> 4) << 6) + (g << 4) + (j & 15); }
    else if (mode == 2) { np = ((n >> 5) << 6) + (n & 31); }
    else if (mode == 3) { np = ((n >> 5) << 6) + 32 + (n & 31); }
    else                { np = n; }
    int kk = koff + k;
    int nt = np >> 4, nl = np & 15, kt = kk >> 5, ko = kk & 31;
    int ln = nl + ((ko >> 3) << 4);
    size_t o = (((size_t)nt * ktiles + kt) * 64 + ln) * 8 + (ko & 7);
    u16 hi = f2b(v);
    u16 lo = f2b(v - b2f(hi));
    dhi[o] = hi; dlo[o] = lo;
}

// ---------- one LSTM layer step ----------
// grid 64 WGs x 512 thr. WG owns 16 h-cols (all 4 gates). wave = mh*4+gate,
// wave computes gates[gate][rows mh*32..+32][16 cols] via 2 MFMA row-tiles.
// hi/lo split: acc += Ah*Bh + Ah*Bl + Al*Bh  (Al*Bl ~ 2^-16 rel, dropped)
template <int KTILES>
__global__ __launch_bounds__(512)
void lstm_stage(const u16 *__restrict__ Ahi, const u16 *__restrict__ Alo,
                const u16 *__restrict__ Whi, const u16 *__restrict__ Wlo,
                const float *__restrict__ bias, float *__restrict__ cbuf,
                u16 *__restrict__ d0hi, u16 *__restrict__ d0lo, int s0,
                u16 *__restrict__ d1hi, u16 *__restrict__ d1lo, int s1) {
    constexpr int KTOT = KTILES * 32;
    const int wg = blockIdx.x;
    const int tid = threadIdx.x;
    const int wave = tid >> 6, lane = tid & 63;
    const int gate = wave & 3, mh = wave >> 2;
    const int r16 = lane & 15, kg = (lane >> 4) << 3;
    const int ntile = (wg << 2) + gate;

    const u16 *ah = Ahi + (((mh << 5) + r16) * KTOT + kg);
    const u16 *al = Alo + (((mh << 5) + r16) * KTOT + kg);
    const u16 *wh = Whi + ((size_t)ntile * KTILES) * 512 + (lane << 3);
    const u16 *wl = Wlo + ((size_t)ntile * KTILES) * 512 + (lane << 3);

    f32x4 acc0 = {0.f, 0.f, 0.f, 0.f}, acc1 = {0.f, 0.f, 0.f, 0.f};
    #pragma unroll 4
    for (int kt = 0; kt < KTILES; ++kt) {
        bf16x8 bh  = ldfrag(wh + (kt << 9));
        bf16x8 bl  = ldfrag(wl + (kt << 9));
        bf16x8 a0h = ldfrag(ah + (kt << 5));
        bf16x8 a1h = ldfrag(ah + 16 * KTOT + (kt << 5));
        bf16x8 a0l = ldfrag(al + (kt << 5));
        bf16x8 a1l = ldfrag(al + 16 * KTOT + (kt << 5));
        acc0 = MFMA16(a0h, bh, acc0);
        acc1 = MFMA16(a1h, bh, acc1);
        acc0 = MFMA16(a0h, bl, acc0);
        acc1 = MFMA16(a1h, bl, acc1);
        acc0 = MFMA16(a0l, bh, acc0);
        acc1 = MFMA16(a1l, bh, acc1);
    }

    __shared__ float gl[4][64][16];   // 16 KiB
    const int hcol = (wg << 4) + r16;
    const float bv = bias[(gate << 10) + hcol];
    #pragma unroll
    for (int j = 0; j < 4; ++j) {
        int r0 = (mh << 5) + ((lane >> 4) << 2) + j;
        float v0 = acc0[j] + bv, v1 = acc1[j] + bv;
        if (gate == 2) { v0 = tanhf(v0); v1 = tanhf(v1); }
        else           { v0 = sigm(v0);  v1 = sigm(v1); }
        gl[gate][r0][r16]      = v0;
        gl[gate][r0 + 16][r16] = v1;
    }
    __syncthreads();

    #pragma unroll
    for (int e = tid; e < 1024; e += 512) {
        int row = e >> 4, col = e & 15;
        int hc = (wg << 4) + col;
        float iv = gl[0][row][col], fv = gl[1][row][col];
        float gv = gl[2][row][col], ov = gl[3][row][col];
        float cn = fv * cbuf[row * HN + hc] + iv * gv;
        cbuf[row * HN + hc] = cn;
        float h = ov * tanhf(cn);
        u16 hh, hl; split2(h, hh, hl);
        size_t o0 = (size_t)row * s0 + hc;
        size_t o1 = (size_t)row * s1 + hc;
        d0hi[o0] = hh; d0lo[o0] = hl;
        d1hi[o1] = hh; d1lo[o1] = hl;
    }
}

// ---------- mu / logvar / z ----------
// grid 8 WGs x 512. WG owns cols wg*32..+32 of mu AND logvar.
// wave = mh*4+sub: sub 0,1 = mu tiles, sub 2,3 = logvar tiles.
__global__ __launch_bounds__(512)
void z_stage(const u16 *__restrict__ Ahi, const u16 *__restrict__ Alo,
             const u16 *__restrict__ Whi, const u16 *__restrict__ Wlo,
             const float *__restrict__ bmu, const float *__restrict__ blv,
             const float *__restrict__ eps, int t,
             float *__restrict__ out, u16 *__restrict__ zhi, u16 *__restrict__ zlo, int sz) {
    constexpr int KTILES = 32, KTOT = 1024;
    const int wg = blockIdx.x;
    const int tid = threadIdx.x;
    const int wave = tid >> 6, lane = tid & 63;
    const int sub = wave & 3, mh = wave >> 2;
    const int r16 = lane & 15, kg = (lane >> 4) << 3;
    const int ntile = (wg << 2) + sub;

    const u16 *ah = Ahi + (((mh << 5) + r16) * KTOT + kg);
    const u16 *al = Alo + (((mh << 5) + r16) * KTOT + kg);
    const u16 *wh = Whi + ((size_t)ntile * KTILES) * 512 + (lane << 3);
    const u16 *wl = Wlo + ((size_t)ntile * KTILES) * 512 + (lane << 3);

    f32x4 acc0 = {0.f, 0.f, 0.f, 0.f}, acc1 = {0.f, 0.f, 0.f, 0.f};
    #pragma unroll 4
    for (int kt = 0; kt < KTILES; ++kt) {
        bf16x8 bh  = ldfrag(wh + (kt << 9));
        bf16x8 bl  = ldfrag(wl + (kt << 9));
        bf16x8 a0h = ldfrag(ah + (kt << 5));
        bf16x8 a1h = ldfrag(ah + 16 * KTOT + (kt << 5));
        bf16x8 a0l = ldfrag(al + (kt << 5));
        bf16x8 a1l = ldfrag(al + 16 * KTOT + (kt << 5));
        acc0 = MFMA16(a0h, bh, acc0);
        acc1 = MFMA16(a1h, bh, acc1);
        acc0 = MFMA16(a0h, bl, acc0);
        acc1 = MFMA16(a1h, bl, acc1);
        acc0 = MFMA16(a0l, bh, acc0);
        acc1 = MFMA16(a1l, bh, acc1);
    }

    __shared__ float gl[4][64][16];
    const int dcol0 = (wg << 5) + ((sub & 1) << 4) + r16;
    const float bv = (sub < 2) ? bmu[dcol0] : blv[dcol0];
    #pragma unroll
    for (int j = 0; j < 4; ++j) {
        int r0 = (mh << 5) + ((lane >> 4) << 2) + j;
        float v0 = fminf(20.f, fmaxf(-20.f, acc0[j] + bv));
        float v1 = fminf(20.f, fmaxf(-20.f, acc1[j] + bv));
        gl[sub][r0][r16]      = v0;
        gl[sub][r0 + 16][r16] = v1;
    }
    __syncthreads();

    #pragma unroll
    for (int e = tid; e < 2048; e += 512) {
        int row = e >> 5, c5 = e & 31;
        int cs = c5 >> 4, cl = c5 & 15;
        float mu = gl[cs][row][cl];
        float lv = gl[2 + cs][row][cl];
        int dcol = (wg << 5) + c5;
        size_t po = ((size_t)row * TN + t) * DN + dcol;
        float ev = eps[po];
        float sd = expf(0.5f * lv);
        float z = mu + ev * sd;
        out[2 * BTD + po] = mu;
        out[3 * BTD + po] = lv;
        out[4 * BTD + po] = z;
        u16 zh, zl; split2(z, zh, zl);
        zhi[(size_t)row * sz + dcol] = zh;
        zlo[(size_t)row * sz + dcol] = zl;
    }
}

// ---------- logits / rec / next-step encoder input ----------
// grid 4 WGs x 512. WG owns 64 output cols. No LDS (pure elementwise epilogue).
__global__ __launch_bounds__(512)
void out_stage(const u16 *__restrict__ Ahi, const u16 *__restrict__ Alo,
               const u16 *__restrict__ Whi, const u16 *__restrict__ Wlo,
               const float *__restrict__ bout, const float *__restrict__ x, int t,
               float *__restrict__ out, u16 *__restrict__ e0hi, u16 *__restrict__ e0lo) {
    constexpr int KTILES = 32, KTOT = 1024;
    const int wg = blockIdx.x;
    const int tid = threadIdx.x;
    const int wave = tid >> 6, lane = tid & 63;
    const int sub = wave & 3, mh = wave >> 2;
    const int r16 = lane & 15, kg = (lane >> 4) << 3;
    const int ntile = (wg << 2) + sub;

    const u16 *ah = Ahi + (((mh << 5) + r16) * KTOT + kg);
    const u16 *al = Alo + (((mh << 5) + r16) * KTOT + kg);
    const u16 *wh = Whi + ((size_t)ntile * KTILES) * 512 + (lane << 3);
    const u16 *wl = Wlo + ((size_t)ntile * KTILES) * 512 + (lane << 3);

    f32x4 acc0 = {0.f, 0.f, 0.f, 0.f}, acc1 = {0.f, 0.f, 0.f, 0.f};
    #pragma unroll 4
    for (int kt = 0; kt < KTILES; ++kt) {
        bf16x8 bh  = ldfrag(wh + (kt << 9));
        bf16x8 bl  = ldfrag(wl + (kt << 9));
        bf16x8 a0h = ldfrag(ah + (kt << 5));
        bf16x8 a1h = ldfrag(ah + 16 * KTOT + (kt << 5));
        bf16x8 a0l = ldfrag(al + (kt << 5));
        bf16x8 a1l = ldfrag(al + 16 * KTOT + (kt << 5));
        acc0 = MFMA16(a0h, bh, acc0);
        acc1 = MFMA16(a1h, bh, acc1);
        acc0 = MFMA16(a0h, bl, acc0);
        acc1 = MFMA16(a1h, bl, acc1);
        acc0 = MFMA16(a0l, bh, acc0);
        acc1 = MFMA16(a1l, bh, acc1);
    }

    const int dcol = (wg << 6) + (sub << 4) + r16;
    const float bv = bout[dcol];
    #pragma unroll
    for (int j = 0; j < 4; ++j) {
        int r0 = (mh << 5) + ((lane >> 4) << 2) + j;
        #pragma unroll
        for (int half = 0; half < 2; ++half) {
            int r = r0 + half * 16;
            float lg = (half ? acc1[j] : acc0[j]) + bv;
            float rc = sigm(lg);
            size_t po = ((size_t)r * TN + t) * DN + dcol;
            out[po] = rc;
            out[BTD + po] = lg;
            if (t + 1 < TN) {
                float xv = x[((size_t)r * TN + t + 1) * DN + dcol];
                float xh = xv - rc;
                u16 h, l;
                split2(xv, h, l);
                e0hi[r * 1536 + dcol] = h;       e0lo[r * 1536 + dcol] = l;
                split2(xh, h, l);
                e0hi[r * 1536 + 256 + dcol] = h; e0lo[r * 1536 + 256 + dcol] = l;
            }
        }
    }
}

extern "C" void kernel_launch(void *const *d_in, const int *in_sizes, int n_in,
                              void *d_out, int out_size, void *d_ws, size_t ws_size,
                              hipStream_t stream) {
    (void)in_sizes; (void)n_in; (void)out_size;
    const float *x     = (const float *)d_in[0];
    const float *eps   = (const float *)d_in[1];
    const float *eWih0 = (const float *)d_in[2];
    const float *eWih  = (const float *)d_in[3];
    const float *eWhh  = (const float *)d_in[4];
    const float *eb    = (const float *)d_in[5];
    const float *Wmu   = (const float *)d_in[6];
    const float *bmu   = (const float *)d_in[7];
    const float *Wlv   = (const float *)d_in[8];
    const float *blv   = (const float *)d_in[9];
    const float *dWih0 = (const float *)d_in[10];
    const float *dWih  = (const float *)d_in[11];
    const float *dWhh  = (const float *)d_in[12];
    const float *db    = (const float *)d_in[13];
    const float *Wout  = (const float *)d_in[14];
    const float *bout  = (const float *)d_in[15];
    float *out = (float *)d_out;

    char *ws = (char *)d_ws;
    size_t cur = 0;
    auto alloc = [&](size_t bytes) -> char * {
        char *p = ws + cur;
        cur = (cur + bytes + 255) & ~(size_t)255;
        return p;
    };

    // packed weights (hi/lo bf16, MFMA fragment order) — repacked EVERY call
    // (harness re-poisons d_ws before each timed launch).
    u16 *Pe0h = (u16 *)alloc((size_t)4096 * 1536 * 2), *Pe0l = (u16 *)alloc((size_t)4096 * 1536 * 2);
    u16 *Pe1h = (u16 *)alloc((size_t)4096 * 2048 * 2), *Pe1l = (u16 *)alloc((size_t)4096 * 2048 * 2);
    u16 *Pe2h = (u16 *)alloc((size_t)4096 * 2048 * 2), *Pe2l = (u16 *)alloc((size_t)4096 * 2048 * 2);
    u16 *Pd0h = (u16 *)alloc((size_t)4096 * 1280 * 2), *Pd0l = (u16 *)alloc((size_t)4096 * 1280 * 2);
    u16 *Pd1h = (u16 *)alloc((size_t)4096 * 2048 * 2), *Pd1l = (u16 *)alloc((size_t)4096 * 2048 * 2);
    u16 *Pd2h = (u16 *)alloc((size_t)4096 * 2048 * 2), *Pd2l = (u16 *)alloc((size_t)4096 * 2048 * 2);
    u16 *Pzh  = (u16 *)alloc((size_t)512 * 1024 * 2),  *Pzl  = (u16 *)alloc((size_t)512 * 1024 * 2);
    u16 *Poh  = (u16 *)alloc((size_t)256 * 1024 * 2),  *Pol  = (u16 *)alloc((size_t)256 * 1024 * 2);

    // activation buffers [parity][plane hi/lo][64][W] + cell state
    size_t zstart = cur;
    u16 *Ae0 = (u16 *)alloc((size_t)2 * 2 * 64 * 1536 * 2);
    u16 *Ae1 = (u16 *)alloc((size_t)2 * 2 * 64 * 2048 * 2);
    u16 *Ae2 = (u16 *)alloc((size_t)2 * 2 * 64 * 2048 * 2);
    u16 *Ad0 = (u16 *)alloc((size_t)2 * 2 * 64 * 1280 * 2);
    u16 *Ad1 = (u16 *)alloc((size_t)2 * 2 * 64 * 2048 * 2);
    u16 *Ad2 = (u16 *)alloc((size_t)2 * 2 * 64 * 2048 * 2);
    u16 *Az  = (u16 *)alloc((size_t)2 * 2 * 64 * 1024 * 2);
    u16 *Ao  = (u16 *)alloc((size_t)2 * 2 * 64 * 1024 * 2);
    float *cb = (float *)alloc((size_t)6 * 64 * 1024 * 4);
    size_t zend = cur;
    if (ws_size < cur) return;   // scratch too small -> bail (will show as mismatch)

    auto AH = [](u16 *base, int W, int par) -> u16 * { return base + (size_t)(par * 2 + 0) * 64 * W; };
    auto AL = [](u16 *base, int W, int par) -> u16 * { return base + (size_t)(par * 2 + 1) * 64 * W; };

    float *c_e0 = cb, *c_e1 = cb + 64 * 1024, *c_e2 = cb + 2 * 64 * 1024;
    float *c_d0 = cb + 3 * 64 * 1024, *c_d1 = cb + 4 * 64 * 1024, *c_d2 = cb + 5 * 64 * 1024;

    // init: zero activations (h(-1)=c(-1)=0) and write t=0 encoder input
    zero_ws<<<2048, 256, 0, stream>>>((uint4 *)(ws + zstart), (zend - zstart) / 16);
    prep_x0<<<64, 256, 0, stream>>>(x, AH(Ae0, 1536, 0), AL(Ae0, 1536, 0));

    auto PK = [&](const float *src, u16 *dh, u16 *dl, int N, int K, int koff, int kt, int mode) {
        int n = N * K;
        pack_w<<<(n + 255) / 256, 256, 0, stream>>>(src, dh, dl, N, K, koff, kt, mode);
    };
    const size_t WSTEP = (size_t)4096 * 1024;
    PK(eWih0, Pe0h, Pe0l, 4096, 512, 0, 48, 1);
    PK(eWhh,  Pe0h, Pe0l, 4096, 1024, 512, 48, 1);
    PK(eWih,  Pe1h, Pe1l, 4096, 1024, 0, 64, 1);
    PK(eWhh + WSTEP, Pe1h, Pe1l, 4096, 1024, 1024, 64, 1);
    PK(eWih + WSTEP, Pe2h, Pe2l, 4096, 1024, 0, 64, 1);
    PK(eWhh + 2 * WSTEP, Pe2h, Pe2l, 4096, 1024, 1024, 64, 1);
    PK(dWih0, Pd0h, Pd0l, 4096, 256, 0, 40, 1);
    PK(dWhh,  Pd0h, Pd0l, 4096, 1024, 256, 40, 1);
    PK(dWih,  Pd1h, Pd1l, 4096, 1024, 0, 64, 1);
    PK(dWhh + WSTEP, Pd1h, Pd1l, 4096, 1024, 1024, 64, 1);
    PK(dWih + WSTEP, Pd2h, Pd2l, 4096, 1024, 0, 64, 1);
    PK(dWhh + 2 * WSTEP, Pd2h, Pd2l, 4096, 1024, 1024, 64, 1);
    PK(Wmu, Pzh, Pzl, 256, 1024, 0, 32, 2);
    PK(Wlv, Pzh, Pzl, 256, 1024, 0, 32, 3);
    PK(Wout, Poh, Pol, 256, 1024, 0, 32, 0);

    for (int t = 0; t < TN; ++t) {
        int p = t & 1, q = p ^ 1;
        // encoder L0: A=[x_t | x_hat | h0(t-1)], K=1536
        lstm_stage<48><<<64, 512, 0, stream>>>(AH(Ae0, 1536, p), AL(Ae0, 1536, p), Pe0h, Pe0l,
            eb, c_e0,
            AH(Ae1, 2048, p), AL(Ae1, 2048, p), 2048,
            AH(Ae0, 1536, q) + 512, AL(Ae0, 1536, q) + 512, 1536);
        // encoder L1: A=[h_e0(t) | h_e1(t-1)], K=2048
        lstm_stage<64><<<64, 512, 0, stream>>>(AH(Ae1, 2048, p), AL(Ae1, 2048, p), Pe1h, Pe1l,
            eb + 4096, c_e1,
            AH(Ae2, 2048, p), AL(Ae2, 2048, p), 2048,
            AH(Ae1, 2048, q) + 1024, AL(Ae1, 2048, q) + 1024, 2048);
        // encoder L2
        lstm_stage<64><<<64, 512, 0, stream>>>(AH(Ae2, 2048, p), AL(Ae2, 2048, p), Pe2h, Pe2l,
            eb + 8192, c_e2,
            AH(Az, 1024, p), AL(Az, 1024, p), 1024,
            AH(Ae2, 2048, q) + 1024, AL(Ae2, 2048, q) + 1024, 2048);
        // mu / logvar / z
        z_stage<<<8, 512, 0, stream>>>(AH(Az, 1024, p), AL(Az, 1024, p), Pzh, Pzl,
            bmu, blv, eps, t, out,
            AH(Ad0, 1280, p), AL(Ad0, 1280, p), 1280);
        // decoder L0: A=[z | h_d0(t-1)], K=1280
        lstm_stage<40><<<64, 512, 0, stream>>>(AH(Ad0, 1280, p), AL(Ad0, 1280, p), Pd0h, Pd0l,
            db, c_d0,
            AH(Ad1, 2048, p), AL(Ad1, 2048, p), 2048,
            AH(Ad0, 1280, q) + 256, AL(Ad0, 1280, q) + 256, 1280);
        // decoder L1
        lstm_stage<64><<<64, 512, 0, stream>>>(AH(Ad1, 2048, p), AL(Ad1, 2048, p), Pd1h, Pd1l,
            db + 4096, c_d1,
            AH(Ad2, 2048, p), AL(Ad2, 2048, p), 2048,
            AH(Ad1, 2048, q) + 1024, AL(Ad1, 2048, q) + 1024, 2048);
        // decoder L2
        lstm_stage<64><<<64, 512, 0, stream>>>(AH(Ad2, 2048, p), AL(Ad2, 2048, p), Pd2h, Pd2l,
            db + 8192, c_d2,
            AH(Ao, 1024, p), AL(Ao, 1024, p), 1024,
            AH(Ad2, 2048, q) + 1024, AL(Ad2, 2048, q) + 1024, 2048);
        // logits / rec / next-step enc input
        out_stage<<<4, 512, 0, stream>>>(AH(Ao, 1024, p), AL(Ao, 1024, p), Poh, Pol,
            bout, x, t, out,
            AH(Ae0, 1536, q), AL(Ae0, 1536, q));
    }
}